// Round 12
// baseline (735.552 us; speedup 1.0000x reference)
//
#include <hip/hip_runtime.h>
#include <hip/hip_fp16.h>

#define NN 100000
#define NE 600000
#define DD 128
#define NL 16
#define SCAN_B 1024
#define SCAN_NB ((NN + SCAN_B - 1) / SCAN_B)   // 98

typedef unsigned int u32x2 __attribute__((ext_vector_type(2)));
typedef unsigned int u32x4 __attribute__((ext_vector_type(4)));
typedef float f32x4 __attribute__((ext_vector_type(4)));

__device__ __forceinline__ float2 h2f(unsigned u) {
    __half2 h = *reinterpret_cast<__half2*>(&u);
    return __half22float2(h);
}

// --- CSR build ---------------------------------------------------------------

__global__ void k_deg(const int* __restrict__ ei, int* __restrict__ deg) {
    int e = blockIdx.x * blockDim.x + threadIdx.x;
    if (e < NE) atomicAdd(&deg[__builtin_nontemporal_load(ei + e)], 1);
}

__global__ void k_bsum(const int* __restrict__ cnt, int* __restrict__ bsum) {
    __shared__ int sh[SCAN_B];
    int i = blockIdx.x * SCAN_B + threadIdx.x;
    sh[threadIdx.x] = (i < NN) ? cnt[i] : 0;
    __syncthreads();
    for (int off = SCAN_B / 2; off > 0; off >>= 1) {
        if (threadIdx.x < off) sh[threadIdx.x] += sh[threadIdx.x + off];
        __syncthreads();
    }
    if (threadIdx.x == 0) bsum[blockIdx.x] = sh[0];
}

__global__ void k_bscan(int* __restrict__ bsum) {
    if (threadIdx.x == 0) {
        int run = 0;
        for (int i = 0; i < SCAN_NB; ++i) { int v = bsum[i]; bsum[i] = run; run += v; }
    }
}

__global__ void k_scan2(const int* __restrict__ cnt, const int* __restrict__ bsum,
                        int* __restrict__ rowptr) {
    __shared__ int sh[SCAN_B];
    int i = blockIdx.x * SCAN_B + threadIdx.x;
    sh[threadIdx.x] = (i < NN) ? cnt[i] : 0;
    __syncthreads();
    for (int off = 1; off < SCAN_B; off <<= 1) {
        int t = (threadIdx.x >= off) ? sh[threadIdx.x - off] : 0;
        __syncthreads();
        sh[threadIdx.x] += t;
        __syncthreads();
    }
    if (i < NN) rowptr[i + 1] = bsum[blockIdx.x] + sh[threadIdx.x];
    if (blockIdx.x == 0 && threadIdx.x == 0) rowptr[0] = 0;
}

// dis folded in: v = rsqrt(deg[r]) * rsqrt(deg[c])
__global__ void k_fill(const int* __restrict__ ei, const int* __restrict__ deg,
                       const int* __restrict__ rowptr, int* __restrict__ cursor,
                       int2* __restrict__ edges) {
    int e = blockIdx.x * blockDim.x + threadIdx.x;
    if (e >= NE) return;
    int r = __builtin_nontemporal_load(ei + e);
    int c = __builtin_nontemporal_load(ei + NE + e);
    int dr = deg[r], dc = deg[c];
    float v = (dr > 0 ? rsqrtf((float)dr) : 0.f) * (dc > 0 ? rsqrtf((float)dc) : 0.f);
    int pos = rowptr[r] + atomicAdd(&cursor[r], 1);
    u32x2 w;
    w.x = (unsigned)c;
    w.y = __float_as_uint(v);
    __builtin_nontemporal_store(w, (u32x2*)(edges + pos));
}

// feat f32 -> fp16
__global__ void k_cvt(const float* __restrict__ f, __half* __restrict__ h) {
    int i = blockIdx.x * blockDim.x + threadIdx.x;   // 4 floats each
    const f32x4 v = __builtin_nontemporal_load((const f32x4*)f + i);
    __half2 a = __floats2half2_rn(v.x, v.y);
    __half2 b = __floats2half2_rn(v.z, v.w);
    uint2 o;
    o.x = *reinterpret_cast<uint*>(&a);
    o.y = *reinterpret_cast<uint*>(&b);
    reinterpret_cast<uint2*>(h)[i] = o;
}

__device__ __forceinline__ void acc8(float* s, uint4 g, float v) {
    float2 f0 = h2f(g.x), f1 = h2f(g.y), f2 = h2f(g.z), f3 = h2f(g.w);
    s[0] += v * f0.x; s[1] += v * f0.y; s[2] += v * f1.x; s[3] += v * f1.y;
    s[4] += v * f2.x; s[5] += v * f2.y; s[6] += v * f3.x; s[7] += v * f3.y;
}

__device__ __forceinline__ void cvt8(float* o, uint4 g) {
    float2 f0 = h2f(g.x), f1 = h2f(g.y), f2 = h2f(g.z), f3 = h2f(g.w);
    o[0] = f0.x; o[1] = f0.y; o[2] = f1.x; o[3] = f1.y;
    o[4] = f2.x; o[5] = f2.y; o[6] = f3.x; o[7] = f3.y;
}

__device__ __forceinline__ void cvt8v(float* o, u32x4 g) {
    float2 f0 = h2f(g.x), f1 = h2f(g.y), f2 = h2f(g.z), f3 = h2f(g.w);
    o[0] = f0.x; o[1] = f0.y; o[2] = f1.x; o[3] = f1.y;
    o[4] = f2.x; o[5] = f2.y; o[6] = f3.x; o[7] = f3.y;
}

// --- per-layer fused kernel (one row per 16-lane quarter-wave, 16B/lane) -----
// MODE 0: xn only
// MODE 1: xn + acc WRITE cA*xm2 + cB*xm1 + c0*o + c1*n   (layer 2; acc poison)
// MODE 2: xn + acc += cA*xm2 + cB*xm1 + c0*o + c1*n      (layers 6,10,14)
// MODE 3: final (layer 15): acc = 0.15*feat + c0*(acc + 0.5*n); no xn
// Streams (edges, xn, acc, xm2/xm1, feat) use nontemporal; gather + own-row stay cached.
template<int MODE>
__global__ __launch_bounds__(256) void k_layer(const int* __restrict__ rowptr,
                                               const int2* __restrict__ edges,
                                               const __half* __restrict__ xo,
                                               __half* __restrict__ xn,
                                               const __half* __restrict__ xm2,
                                               const __half* __restrict__ xm1,
                                               float* __restrict__ acc,
                                               const float* __restrict__ feat,
                                               float fb, float cA, float cB,
                                               float c0, float c1) {
    const int qw = threadIdx.x >> 4;        // 0..15 quarter-waves per block
    const int lane = threadIdx.x & 15;
    const int r = blockIdx.x * 16 + qw;     // 6250*16 == NN exactly
    int p = rowptr[r];
    const int end = rowptr[r + 1];
    const int d8 = lane * 8;                // half index
    float s[8] = {0.f, 0.f, 0.f, 0.f, 0.f, 0.f, 0.f, 0.f};
    for (; p + 3 < end; p += 4) {
        u32x2 e0 = __builtin_nontemporal_load((const u32x2*)(edges + p));
        u32x2 e1 = __builtin_nontemporal_load((const u32x2*)(edges + p + 1));
        u32x2 e2 = __builtin_nontemporal_load((const u32x2*)(edges + p + 2));
        u32x2 e3 = __builtin_nontemporal_load((const u32x2*)(edges + p + 3));
        const uint4 g0 = *reinterpret_cast<const uint4*>(xo + (size_t)e0.x * DD + d8);
        const uint4 g1 = *reinterpret_cast<const uint4*>(xo + (size_t)e1.x * DD + d8);
        const uint4 g2 = *reinterpret_cast<const uint4*>(xo + (size_t)e2.x * DD + d8);
        const uint4 g3 = *reinterpret_cast<const uint4*>(xo + (size_t)e3.x * DD + d8);
        acc8(s, g0, __uint_as_float(e0.y));
        acc8(s, g1, __uint_as_float(e1.y));
        acc8(s, g2, __uint_as_float(e2.y));
        acc8(s, g3, __uint_as_float(e3.y));
    }
    for (; p < end; ++p) {
        u32x2 ev = __builtin_nontemporal_load((const u32x2*)(edges + p));
        const uint4 gv = *reinterpret_cast<const uint4*>(xo + (size_t)ev.x * DD + d8);
        acc8(s, gv, __uint_as_float(ev.y));
    }
    const size_t ih = (size_t)r * DD + d8;        // half index
    float o[8];
    cvt8(o, *reinterpret_cast<const uint4*>(xo + ih));
    float n[8];
#pragma unroll
    for (int k = 0; k < 8; ++k) n[k] = (1.f - fb) * o[k] + fb * s[k];

    if (MODE == 3) {
        const f32x4 fA = __builtin_nontemporal_load((const f32x4*)(feat + ih));
        const f32x4 fB = __builtin_nontemporal_load((const f32x4*)(feat + ih + 4));
        const f32x4 aA = __builtin_nontemporal_load((const f32x4*)(acc + ih));
        const f32x4 aB = __builtin_nontemporal_load((const f32x4*)(acc + ih + 4));
        f32x4 oA, oB;
        oA.x = 0.15f * fA.x + c0 * (aA.x + 0.5f * n[0]);
        oA.y = 0.15f * fA.y + c0 * (aA.y + 0.5f * n[1]);
        oA.z = 0.15f * fA.z + c0 * (aA.z + 0.5f * n[2]);
        oA.w = 0.15f * fA.w + c0 * (aA.w + 0.5f * n[3]);
        oB.x = 0.15f * fB.x + c0 * (aB.x + 0.5f * n[4]);
        oB.y = 0.15f * fB.y + c0 * (aB.y + 0.5f * n[5]);
        oB.z = 0.15f * fB.z + c0 * (aB.z + 0.5f * n[6]);
        oB.w = 0.15f * fB.w + c0 * (aB.w + 0.5f * n[7]);
        __builtin_nontemporal_store(oA, (f32x4*)(acc + ih));
        __builtin_nontemporal_store(oB, (f32x4*)(acc + ih + 4));
    } else {
        __half2 p0 = __floats2half2_rn(n[0], n[1]);
        __half2 p1 = __floats2half2_rn(n[2], n[3]);
        __half2 p2 = __floats2half2_rn(n[4], n[5]);
        __half2 p3 = __floats2half2_rn(n[6], n[7]);
        u32x4 w;
        w.x = *reinterpret_cast<uint*>(&p0);
        w.y = *reinterpret_cast<uint*>(&p1);
        w.z = *reinterpret_cast<uint*>(&p2);
        w.w = *reinterpret_cast<uint*>(&p3);
        __builtin_nontemporal_store(w, (u32x4*)(xn + ih));
        if (MODE == 1 || MODE == 2) {
            float m2[8], m1[8];
            cvt8v(m2, __builtin_nontemporal_load((const u32x4*)(xm2 + ih)));
            cvt8v(m1, __builtin_nontemporal_load((const u32x4*)(xm1 + ih)));
            float t[8];
#pragma unroll
            for (int k = 0; k < 8; ++k)
                t[k] = cA * m2[k] + cB * m1[k] + c0 * o[k] + c1 * n[k];
            if (MODE == 1) {
                f32x4 aA, aB;
                aA.x = t[0]; aA.y = t[1]; aA.z = t[2]; aA.w = t[3];
                aB.x = t[4]; aB.y = t[5]; aB.z = t[6]; aB.w = t[7];
                __builtin_nontemporal_store(aA, (f32x4*)(acc + ih));
                __builtin_nontemporal_store(aB, (f32x4*)(acc + ih + 4));
            } else {
                f32x4 aA = __builtin_nontemporal_load((const f32x4*)(acc + ih));
                f32x4 aB = __builtin_nontemporal_load((const f32x4*)(acc + ih + 4));
                aA.x += t[0]; aA.y += t[1]; aA.z += t[2]; aA.w += t[3];
                aB.x += t[4]; aB.y += t[5]; aB.z += t[6]; aB.w += t[7];
                __builtin_nontemporal_store(aA, (f32x4*)(acc + ih));
                __builtin_nontemporal_store(aB, (f32x4*)(acc + ih + 4));
            }
        }
    }
}

// 4 layers' negative edges in one launch: acc[r] += negco[lg] * x_{lg}[c]
__global__ void k_neg4(const int* __restrict__ ng, const __half* __restrict__ s0,
                       const __half* __restrict__ s1, const __half* __restrict__ s2,
                       const __half* __restrict__ s3, float* __restrict__ acc,
                       float n0, float n1, float n2, float n3) {
    int tid = blockIdx.x * blockDim.x + threadIdx.x;
    int e4 = tid >> 5;
    if (e4 >= 480) return;
    int lg = e4 / 120;
    int e = e4 - lg * 120;
    const int* nl = ng + lg * 120;
    const __half* x = (lg == 0) ? s0 : (lg == 1) ? s1 : (lg == 2) ? s2 : s3;
    float coef = (lg == 0) ? n0 : (lg == 1) ? n1 : (lg == 2) ? n2 : n3;
    int d4 = (tid & 31) << 2;
    int r = nl[e];
    int c = (e < 60) ? nl[60 + e] : nl[e - 60];
    const uint2 g = *reinterpret_cast<const uint2*>(x + (size_t)c * DD + d4);
    float2 f0 = h2f(g.x);
    float2 f1 = h2f(g.y);
    float* ap = acc + (size_t)r * DD + d4;
    atomicAdd(ap + 0, coef * f0.x);
    atomicAdd(ap + 1, coef * f0.y);
    atomicAdd(ap + 2, coef * f1.x);
    atomicAdd(ap + 3, coef * f1.y);
}

extern "C" void kernel_launch(void* const* d_in, const int* in_sizes, int n_in,
                              void* d_out, int out_size, void* d_ws, size_t ws_size,
                              hipStream_t stream) {
    const float* feat = (const float*)d_in[0];
    const int* ei = (const int*)d_in[1];
    const int* negei = (const int*)d_in[2];
    float* out = (float*)d_out;                      // doubles as acc

    __half* S[4];
    S[0] = (__half*)d_ws;                            // NN*DD half each
    S[1] = S[0] + (size_t)NN * DD;
    S[2] = S[1] + (size_t)NN * DD;
    S[3] = S[2] + (size_t)NN * DD;
    int2* edges = (int2*)(S[3] + (size_t)NN * DD);   // NE int2
    int* rowptr = (int*)(edges + NE);                // NN+1
    int* deg = rowptr + (NN + 1);                    // NN
    int* cursor = deg + NN;                          // NN (contiguous with deg)
    int* bsum = cursor + NN;                         // SCAN_NB

    hipMemsetAsync(deg, 0, 2 * NN * sizeof(int), stream);   // deg + cursor
    k_deg<<<(NE + 255) / 256, 256, 0, stream>>>(ei, deg);
    k_bsum<<<SCAN_NB, SCAN_B, 0, stream>>>(deg, bsum);
    k_bscan<<<1, 64, 0, stream>>>(bsum);
    k_scan2<<<SCAN_NB, SCAN_B, 0, stream>>>(deg, bsum, rowptr);
    k_fill<<<(NE + 255) / 256, 256, 0, stream>>>(ei, deg, rowptr, cursor, edges);
    k_cvt<<<(NN * DD / 4) / 256, 256, 0, stream>>>(feat, S[0]);

    // host-side coefficient tables (double precision)
    const double cc = 120.0 / 100000.0 + 2.0;
    double bv[NL], coef[NL], negco[NL];
    {
        double b = 1.0, bn = 1.0;
        for (int l = 0; l < NL; ++l) {
            double al = (1.0 - bn) + 2.0 * bn / cc;
            bv[l] = b;
            coef[l] = 0.5 * al + (l > 0 ? 0.5 : 0.0);
            negco[l] = -0.5 * bn / cc;
            b *= 0.9;
            bn *= 0.5;
        }
    }

    const int lg = NN / 16;                 // 6250 blocks, 16 rows each (exact)
    const int ngrid = (480 * 32 + 255) / 256;

    for (int l = 0; l < NL - 1; ++l) {
        const __half* xo = S[l & 3];
        __half* xn = S[(l + 1) & 3];
        float fb = (float)bv[l];
        bool accl = (l == 2 || l == 6 || l == 10 || l == 14);
        if (l == 2) {
            k_layer<1><<<lg, 256, 0, stream>>>(rowptr, edges, xo, xn,
                                               S[0], S[1], out, feat, fb,
                                               (float)coef[0], (float)coef[1],
                                               (float)coef[2], (float)coef[3]);
        } else if (accl) {
            k_layer<2><<<lg, 256, 0, stream>>>(rowptr, edges, xo, xn,
                                               S[(l - 2) & 3], S[(l - 1) & 3], out, feat, fb,
                                               (float)coef[l - 2], (float)coef[l - 1],
                                               (float)coef[l], (float)coef[l + 1]);
        } else {
            k_layer<0><<<lg, 256, 0, stream>>>(rowptr, edges, xo, xn,
                                               nullptr, nullptr, nullptr, nullptr, fb,
                                               0.f, 0.f, 0.f, 0.f);
        }
        if (accl) {
            int g = (l - 2) / 4;            // layers 4g..4g+3, x_{4g+k} in S[k]
            k_neg4<<<ngrid, 256, 0, stream>>>(negei + 4 * g * 120,
                                              S[0], S[1], S[2], S[3], out,
                                              (float)negco[4 * g], (float)negco[4 * g + 1],
                                              (float)negco[4 * g + 2], (float)negco[4 * g + 3]);
        }
    }
    // layer 15: fused final (x15 lives in S[3])
    k_layer<3><<<lg, 256, 0, stream>>>(rowptr, edges, S[3], nullptr,
                                       nullptr, nullptr, out, feat,
                                       (float)bv[15], 0.f, 0.f, 0.85f / 16.f, 0.f);
}

// Round 13
// 665.733 us; speedup vs baseline: 1.1049x; 1.1049x over previous
//
#include <hip/hip_runtime.h>
#include <hip/hip_fp16.h>

#define NN 100000
#define NE 600000
#define DD 128
#define NL 16
#define SCAN_B 1024
#define SCAN_NB ((NN + SCAN_B - 1) / SCAN_B)   // 98

// --- CSR build ---------------------------------------------------------------

__global__ void k_deg(const int* __restrict__ ei, int* __restrict__ deg) {
    int t = blockIdx.x * blockDim.x + threadIdx.x;   // 2 edges per thread
    if (t * 2 >= NE) return;
    int2 e = *reinterpret_cast<const int2*>(ei + t * 2);
    atomicAdd(&deg[e.x], 1);
    atomicAdd(&deg[e.y], 1);
}

__global__ void k_bsum(const int* __restrict__ cnt, int* __restrict__ bsum) {
    __shared__ int sh[SCAN_B];
    int i = blockIdx.x * SCAN_B + threadIdx.x;
    sh[threadIdx.x] = (i < NN) ? cnt[i] : 0;
    __syncthreads();
    for (int off = SCAN_B / 2; off > 0; off >>= 1) {
        if (threadIdx.x < off) sh[threadIdx.x] += sh[threadIdx.x + off];
        __syncthreads();
    }
    if (threadIdx.x == 0) bsum[blockIdx.x] = sh[0];
}

__global__ void k_bscan(int* __restrict__ bsum) {
    if (threadIdx.x == 0) {
        int run = 0;
        for (int i = 0; i < SCAN_NB; ++i) { int v = bsum[i]; bsum[i] = run; run += v; }
    }
}

__global__ void k_scan2(const int* __restrict__ cnt, const int* __restrict__ bsum,
                        int* __restrict__ rowptr) {
    __shared__ int sh[SCAN_B];
    int i = blockIdx.x * SCAN_B + threadIdx.x;
    sh[threadIdx.x] = (i < NN) ? cnt[i] : 0;
    __syncthreads();
    for (int off = 1; off < SCAN_B; off <<= 1) {
        int t = (threadIdx.x >= off) ? sh[threadIdx.x - off] : 0;
        __syncthreads();
        sh[threadIdx.x] += t;
        __syncthreads();
    }
    if (i < NN) rowptr[i + 1] = bsum[blockIdx.x] + sh[threadIdx.x];
    if (blockIdx.x == 0 && threadIdx.x == 0) rowptr[0] = 0;
}

// dis folded in: v = rsqrt(deg[r]) * rsqrt(deg[c])
__global__ void k_fill(const int* __restrict__ ei, const int* __restrict__ deg,
                       const int* __restrict__ rowptr, int* __restrict__ cursor,
                       int2* __restrict__ edges) {
    int e = blockIdx.x * blockDim.x + threadIdx.x;
    if (e >= NE) return;
    int r = ei[e], c = ei[NE + e];
    int dr = deg[r], dc = deg[c];
    float v = (dr > 0 ? rsqrtf((float)dr) : 0.f) * (dc > 0 ? rsqrtf((float)dc) : 0.f);
    int pos = rowptr[r] + atomicAdd(&cursor[r], 1);
    edges[pos] = make_int2(c, __float_as_int(v));
}

// feat f32 -> fp16
__global__ void k_cvt(const float* __restrict__ f, __half* __restrict__ h) {
    int i = blockIdx.x * blockDim.x + threadIdx.x;   // 4 floats each
    const float4 v = reinterpret_cast<const float4*>(f)[i];
    __half2 a = __floats2half2_rn(v.x, v.y);
    __half2 b = __floats2half2_rn(v.z, v.w);
    uint2 o;
    o.x = *reinterpret_cast<uint*>(&a);
    o.y = *reinterpret_cast<uint*>(&b);
    reinterpret_cast<uint2*>(h)[i] = o;
}

__device__ __forceinline__ float2 h2f(unsigned u) {
    __half2 h = *reinterpret_cast<__half2*>(&u);
    return __half22float2(h);
}

__device__ __forceinline__ void acc8(float* s, uint4 g, float v) {
    float2 f0 = h2f(g.x), f1 = h2f(g.y), f2 = h2f(g.z), f3 = h2f(g.w);
    s[0] += v * f0.x; s[1] += v * f0.y; s[2] += v * f1.x; s[3] += v * f1.y;
    s[4] += v * f2.x; s[5] += v * f2.y; s[6] += v * f3.x; s[7] += v * f3.y;
}

__device__ __forceinline__ void cvt8(float* o, uint4 g) {
    float2 f0 = h2f(g.x), f1 = h2f(g.y), f2 = h2f(g.z), f3 = h2f(g.w);
    o[0] = f0.x; o[1] = f0.y; o[2] = f1.x; o[3] = f1.y;
    o[4] = f2.x; o[5] = f2.y; o[6] = f3.x; o[7] = f3.y;
}

// --- per-layer fused kernel (one row per 16-lane quarter-wave, 16B/lane) -----
// MODE 0: xn only
// MODE 1: xn + acc WRITE cA*xm2 + cB*xm1 + c0*o + c1*n   (layer 2; acc poison)
// MODE 2: xn + acc += cA*xm2 + cB*xm1 + c0*o + c1*n      (layers 6,10,14)
// MODE 3: final (layer 15): acc = 0.15*feat + c0*(acc + 0.5*n); no xn
template<int MODE>
__global__ __launch_bounds__(256) void k_layer(const int* __restrict__ rowptr,
                                               const int2* __restrict__ edges,
                                               const __half* __restrict__ xo,
                                               __half* __restrict__ xn,
                                               const __half* __restrict__ xm2,
                                               const __half* __restrict__ xm1,
                                               float* __restrict__ acc,
                                               const float* __restrict__ feat,
                                               float fb, float cA, float cB,
                                               float c0, float c1) {
    const int qw = threadIdx.x >> 4;        // 0..15 quarter-waves per block
    const int lane = threadIdx.x & 15;
    const int r = blockIdx.x * 16 + qw;     // 6250*16 == NN exactly
    int p = rowptr[r];
    const int end = rowptr[r + 1];
    const int d8 = lane * 8;                // half index
    float s[8] = {0.f, 0.f, 0.f, 0.f, 0.f, 0.f, 0.f, 0.f};
    for (; p + 3 < end; p += 4) {
        int2 e0 = edges[p];
        int2 e1 = edges[p + 1];
        int2 e2 = edges[p + 2];
        int2 e3 = edges[p + 3];
        const uint4 g0 = *reinterpret_cast<const uint4*>(xo + (size_t)e0.x * DD + d8);
        const uint4 g1 = *reinterpret_cast<const uint4*>(xo + (size_t)e1.x * DD + d8);
        const uint4 g2 = *reinterpret_cast<const uint4*>(xo + (size_t)e2.x * DD + d8);
        const uint4 g3 = *reinterpret_cast<const uint4*>(xo + (size_t)e3.x * DD + d8);
        acc8(s, g0, __int_as_float(e0.y));
        acc8(s, g1, __int_as_float(e1.y));
        acc8(s, g2, __int_as_float(e2.y));
        acc8(s, g3, __int_as_float(e3.y));
    }
    for (; p < end; ++p) {
        int2 ev = edges[p];
        const uint4 gv = *reinterpret_cast<const uint4*>(xo + (size_t)ev.x * DD + d8);
        acc8(s, gv, __int_as_float(ev.y));
    }
    const size_t ih = (size_t)r * DD + d8;        // half index
    float o[8];
    cvt8(o, *reinterpret_cast<const uint4*>(xo + ih));
    float n[8];
#pragma unroll
    for (int k = 0; k < 8; ++k) n[k] = (1.f - fb) * o[k] + fb * s[k];

    if (MODE == 3) {
        const float4 fA = *reinterpret_cast<const float4*>(feat + ih);
        const float4 fB = *reinterpret_cast<const float4*>(feat + ih + 4);
        const float4 aA = *reinterpret_cast<const float4*>(acc + ih);
        const float4 aB = *reinterpret_cast<const float4*>(acc + ih + 4);
        float4 oA, oB;
        oA.x = 0.15f * fA.x + c0 * (aA.x + 0.5f * n[0]);
        oA.y = 0.15f * fA.y + c0 * (aA.y + 0.5f * n[1]);
        oA.z = 0.15f * fA.z + c0 * (aA.z + 0.5f * n[2]);
        oA.w = 0.15f * fA.w + c0 * (aA.w + 0.5f * n[3]);
        oB.x = 0.15f * fB.x + c0 * (aB.x + 0.5f * n[4]);
        oB.y = 0.15f * fB.y + c0 * (aB.y + 0.5f * n[5]);
        oB.z = 0.15f * fB.z + c0 * (aB.z + 0.5f * n[6]);
        oB.w = 0.15f * fB.w + c0 * (aB.w + 0.5f * n[7]);
        *reinterpret_cast<float4*>(acc + ih) = oA;
        *reinterpret_cast<float4*>(acc + ih + 4) = oB;
    } else {
        __half2 p0 = __floats2half2_rn(n[0], n[1]);
        __half2 p1 = __floats2half2_rn(n[2], n[3]);
        __half2 p2 = __floats2half2_rn(n[4], n[5]);
        __half2 p3 = __floats2half2_rn(n[6], n[7]);
        uint4 w;
        w.x = *reinterpret_cast<uint*>(&p0);
        w.y = *reinterpret_cast<uint*>(&p1);
        w.z = *reinterpret_cast<uint*>(&p2);
        w.w = *reinterpret_cast<uint*>(&p3);
        *reinterpret_cast<uint4*>(xn + ih) = w;
        if (MODE == 1 || MODE == 2) {
            float m2[8], m1[8];
            cvt8(m2, *reinterpret_cast<const uint4*>(xm2 + ih));
            cvt8(m1, *reinterpret_cast<const uint4*>(xm1 + ih));
            float t[8];
#pragma unroll
            for (int k = 0; k < 8; ++k)
                t[k] = cA * m2[k] + cB * m1[k] + c0 * o[k] + c1 * n[k];
            if (MODE == 1) {
                float4 aA, aB;
                aA.x = t[0]; aA.y = t[1]; aA.z = t[2]; aA.w = t[3];
                aB.x = t[4]; aB.y = t[5]; aB.z = t[6]; aB.w = t[7];
                *reinterpret_cast<float4*>(acc + ih) = aA;
                *reinterpret_cast<float4*>(acc + ih + 4) = aB;
            } else {
                float4 aA = *reinterpret_cast<const float4*>(acc + ih);
                float4 aB = *reinterpret_cast<const float4*>(acc + ih + 4);
                aA.x += t[0]; aA.y += t[1]; aA.z += t[2]; aA.w += t[3];
                aB.x += t[4]; aB.y += t[5]; aB.z += t[6]; aB.w += t[7];
                *reinterpret_cast<float4*>(acc + ih) = aA;
                *reinterpret_cast<float4*>(acc + ih + 4) = aB;
            }
        }
    }
}

// 4 layers' negative edges in one launch: acc[r] += negco[lg] * x_{lg}[c]
__global__ void k_neg4(const int* __restrict__ ng, const __half* __restrict__ s0,
                       const __half* __restrict__ s1, const __half* __restrict__ s2,
                       const __half* __restrict__ s3, float* __restrict__ acc,
                       float n0, float n1, float n2, float n3) {
    int tid = blockIdx.x * blockDim.x + threadIdx.x;
    int e4 = tid >> 5;
    if (e4 >= 480) return;
    int lg = e4 / 120;
    int e = e4 - lg * 120;
    const int* nl = ng + lg * 120;
    const __half* x = (lg == 0) ? s0 : (lg == 1) ? s1 : (lg == 2) ? s2 : s3;
    float coef = (lg == 0) ? n0 : (lg == 1) ? n1 : (lg == 2) ? n2 : n3;
    int d4 = (tid & 31) << 2;
    int r = nl[e];
    int c = (e < 60) ? nl[60 + e] : nl[e - 60];
    const uint2 g = *reinterpret_cast<const uint2*>(x + (size_t)c * DD + d4);
    float2 f0 = h2f(g.x);
    float2 f1 = h2f(g.y);
    float* ap = acc + (size_t)r * DD + d4;
    atomicAdd(ap + 0, coef * f0.x);
    atomicAdd(ap + 1, coef * f0.y);
    atomicAdd(ap + 2, coef * f1.x);
    atomicAdd(ap + 3, coef * f1.y);
}

extern "C" void kernel_launch(void* const* d_in, const int* in_sizes, int n_in,
                              void* d_out, int out_size, void* d_ws, size_t ws_size,
                              hipStream_t stream) {
    const float* feat = (const float*)d_in[0];
    const int* ei = (const int*)d_in[1];
    const int* negei = (const int*)d_in[2];
    float* out = (float*)d_out;                      // doubles as acc

    __half* S[4];
    S[0] = (__half*)d_ws;                            // NN*DD half each
    S[1] = S[0] + (size_t)NN * DD;
    S[2] = S[1] + (size_t)NN * DD;
    S[3] = S[2] + (size_t)NN * DD;
    int2* edges = (int2*)(S[3] + (size_t)NN * DD);   // NE int2
    int* rowptr = (int*)(edges + NE);                // NN+1
    int* deg = rowptr + (NN + 1);                    // NN
    int* cursor = deg + NN;                          // NN (contiguous with deg)
    int* bsum = cursor + NN;                         // SCAN_NB

    hipMemsetAsync(deg, 0, 2 * NN * sizeof(int), stream);   // deg + cursor
    k_deg<<<(NE / 2 + 255) / 256, 256, 0, stream>>>(ei, deg);
    k_bsum<<<SCAN_NB, SCAN_B, 0, stream>>>(deg, bsum);
    k_bscan<<<1, 64, 0, stream>>>(bsum);
    k_scan2<<<SCAN_NB, SCAN_B, 0, stream>>>(deg, bsum, rowptr);
    k_fill<<<(NE + 255) / 256, 256, 0, stream>>>(ei, deg, rowptr, cursor, edges);
    k_cvt<<<(NN * DD / 4) / 256, 256, 0, stream>>>(feat, S[0]);

    // host-side coefficient tables (double precision)
    const double cc = 120.0 / 100000.0 + 2.0;
    double bv[NL], coef[NL], negco[NL];
    {
        double b = 1.0, bn = 1.0;
        for (int l = 0; l < NL; ++l) {
            double al = (1.0 - bn) + 2.0 * bn / cc;
            bv[l] = b;
            coef[l] = 0.5 * al + (l > 0 ? 0.5 : 0.0);
            negco[l] = -0.5 * bn / cc;
            b *= 0.9;
            bn *= 0.5;
        }
    }

    const int lg = NN / 16;                 // 6250 blocks, 16 rows each (exact)
    const int ngrid = (480 * 32 + 255) / 256;

    for (int l = 0; l < NL - 1; ++l) {
        const __half* xo = S[l & 3];
        __half* xn = S[(l + 1) & 3];
        float fb = (float)bv[l];
        bool accl = (l == 2 || l == 6 || l == 10 || l == 14);
        if (l == 2) {
            k_layer<1><<<lg, 256, 0, stream>>>(rowptr, edges, xo, xn,
                                               S[0], S[1], out, feat, fb,
                                               (float)coef[0], (float)coef[1],
                                               (float)coef[2], (float)coef[3]);
        } else if (accl) {
            k_layer<2><<<lg, 256, 0, stream>>>(rowptr, edges, xo, xn,
                                               S[(l - 2) & 3], S[(l - 1) & 3], out, feat, fb,
                                               (float)coef[l - 2], (float)coef[l - 1],
                                               (float)coef[l], (float)coef[l + 1]);
        } else {
            k_layer<0><<<lg, 256, 0, stream>>>(rowptr, edges, xo, xn,
                                               nullptr, nullptr, nullptr, nullptr, fb,
                                               0.f, 0.f, 0.f, 0.f);
        }
        if (accl) {
            int g = (l - 2) / 4;            // layers 4g..4g+3, x_{4g+k} in S[k]
            k_neg4<<<ngrid, 256, 0, stream>>>(negei + 4 * g * 120,
                                              S[0], S[1], S[2], S[3], out,
                                              (float)negco[4 * g], (float)negco[4 * g + 1],
                                              (float)negco[4 * g + 2], (float)negco[4 * g + 3]);
        }
    }
    // layer 15: fused final (x15 lives in S[3])
    k_layer<3><<<lg, 256, 0, stream>>>(rowptr, edges, S[3], nullptr,
                                       nullptr, nullptr, out, feat,
                                       (float)bv[15], 0.f, 0.f, 0.85f / 16.f, 0.f);
}